// Round 7
// baseline (277.115 us; speedup 1.0000x reference)
//
#include <hip/hip_runtime.h>
#include <hip/hip_bf16.h>
#include <stdint.h>

// EvolvedLoopLinear: out[b,j] = sum_i x[b,i]*W[j,i] + b[j]
// M=8192, N=4096, K=4096. fp32 in/out, bf16 MFMA compute.
// Round 7: MFMA lagged one phase behind its ds_reads. Reads/stages/vmcnt/
// barriers at the SAME phases as round 6 (ledger unchanged); only the
// quadrant-to-phase map shifts: P2:q0 P3:q1 P4:q2 P5:q3 P6:q0' P7:q1'
// P8:q2' P1+:q3'. Each phase: issue reads (no wait) -> MFMA prev set ->
// lgkmcnt(0) drain own reads (they flew under the MFMA) -> barrier.
// Per-wave drain-before-barrier preserved => WAR publication discipline
// identical to round 6. T1 XCD swizzle, T2 XOR swizzle (0 conflicts),
// T4 counted vmcnt(6), T5 setprio, fence discipline from round 4.

typedef __bf16 bf16_t;
typedef __bf16 bf16x8 __attribute__((ext_vector_type(8)));
typedef float  f32x4  __attribute__((ext_vector_type(4)));

#define M_DIM 8192
#define N_DIM 4096
#define K_DIM 4096
#define NT    (K_DIM / 64)    // 64 K-tiles of BK=64
#define NITER (NT / 2)        // 32 iterations, 2 K-tiles each

#define GLD16(gp, lp) __builtin_amdgcn_global_load_lds(                    \
    (const __attribute__((address_space(1))) void*)(gp),                   \
    (__attribute__((address_space(3))) void*)(lp), 16, 0, 0)

#define MFMA(a, b, c) __builtin_amdgcn_mfma_f32_16x16x32_bf16((a), (b), (c), 0, 0, 0)

#define FENCE() asm volatile("" ::: "memory")

// ---------------- fp32 -> bf16 convert (vectorized, grid-stride) -----------
__global__ void __launch_bounds__(256) cvt_f32_bf16(
    const float* __restrict__ in, bf16_t* __restrict__ out, long n8)
{
    long i0 = (long)blockIdx.x * blockDim.x + threadIdx.x;
    long stride = (long)gridDim.x * blockDim.x;
    for (long i = i0; i < n8; i += stride) {
        const float4* p = (const float4*)(in + i * 8);
        float4 a = p[0];
        float4 b = p[1];
        bf16x8 o;
        o[0] = (bf16_t)a.x; o[1] = (bf16_t)a.y; o[2] = (bf16_t)a.z; o[3] = (bf16_t)a.w;
        o[4] = (bf16_t)b.x; o[5] = (bf16_t)b.y; o[6] = (bf16_t)b.z; o[7] = (bf16_t)b.w;
        *(bf16x8*)(out + i * 8) = o;
    }
}

// ---------------- 256x256 8-phase bf16 GEMM (A,B row-major [*,K]) ----------
// LDS per parity buffer q (32768 el): Am0 @0, Am1 @8192, Bn0 @16384,
// Bn1 @24576. Chunk swizzle within each region: slot = chunk ^ (rho&7).
__global__ void __launch_bounds__(512, 1) gemm_256_8ph(
    const bf16_t* __restrict__ A, const bf16_t* __restrict__ B,
    const float* __restrict__ bias, float* __restrict__ C)
{
    __shared__ bf16_t sm[2 * 32768];   // 128 KiB

    // XCD-aware bijective swizzle (gridDim = 512, divisible by 8)
    const int nwg = gridDim.x;
    const int bid = blockIdx.x;
    const int cpx = nwg >> 3;
    const int swz = (bid & 7) * cpx + (bid >> 3);
    const int NBN = N_DIM / 256;                       // 16
    const long blockM = (long)(swz / NBN) * 256;
    const long blockN = (long)(swz % NBN) * 256;

    const int t    = threadIdx.x;
    const int lane = t & 63;
    const int wid  = t >> 6;        // 8 waves: 2 (M) x 4 (N)
    const int wr   = wid >> 2;      // 0..1 -> 128 rows each
    const int wc   = wid & 3;       // 0..3 -> 64 cols each
    const int l15  = lane & 15;
    const int lk   = lane >> 4;     // 0..3

    // staging: LDS dest linear (t*16B within region line); global src row
    // per region mapping, chunk carries inverse swizzle.
    const int cg  = (t & 7) ^ ((t >> 3) & 7);
    const int rA0 = (t >> 3);                                  // A line-0 row
    const int rB0 = ((t >> 3) & 31) | (((t >> 3) & 32) << 1);  // B line-0 row
    const bf16_t* gA = A + (blockM + rA0) * (long)K_DIM + cg * 8;
    const bf16_t* gB = B + (blockN + rB0) * (long)K_DIM + cg * 8;
    const int dstT = t * 8;         // 16 B per thread, linear within line

    // read side: fragment rho&7 == l15&7 for all fragments
    const int swzr = l15 & 7;
    const int cOff0 = ((0 * 4 + lk) ^ swzr) << 3;
    const int cOff1 = ((1 * 4 + lk) ^ swzr) << 3;
    const int aBase = wr * 4096 + l15 * 64;            // within Am region
    const int bBase = 16384 + wc * 2048 + l15 * 64;    // within buffer (Bn0)

    f32x4 acc[8][4] = {};

#define STAGE_A(q, tk, h) do {                                             \
    const bf16_t* _g = gA + (long)(tk) * 64 + (long)(h) * 64 * K_DIM;      \
    bf16_t* _l = (bf16_t*)sm + (q) * 32768 + (h) * 8192 + dstT;            \
    GLD16(_g,                _l);                                          \
    GLD16(_g + 128L * K_DIM, _l + 4096); } while (0)

#define STAGE_B(q, tk, h) do {                                             \
    const bf16_t* _g = gB + (long)(tk) * 64 + (long)(h) * 32 * K_DIM;      \
    bf16_t* _l = (bf16_t*)sm + (q) * 32768 + 16384 + (h) * 8192 + dstT;    \
    GLD16(_g,                _l);                                          \
    GLD16(_g + 128L * K_DIM, _l + 4096); } while (0)

    bf16x8 a0[4][2], a1[4][2], b0[2][2], b1[2][2];

    // fragment-read groups (issue only; no use in same phase)
#define READ_A0B0(s) do {                                                  \
    _Pragma("unroll") for (int m = 0; m < 4; ++m) {                        \
        a0[m][0] = *(const bf16x8*)((s) + aBase + m * 1024 + cOff0);       \
        a0[m][1] = *(const bf16x8*)((s) + aBase + m * 1024 + cOff1);       \
    }                                                                      \
    _Pragma("unroll") for (int n = 0; n < 2; ++n) {                        \
        b0[n][0] = *(const bf16x8*)((s) + bBase + n * 1024 + cOff0);       \
        b0[n][1] = *(const bf16x8*)((s) + bBase + n * 1024 + cOff1);       \
    } } while (0)

#define READ_B1(s) do {                                                    \
    _Pragma("unroll") for (int n = 0; n < 2; ++n) {                        \
        b1[n][0] = *(const bf16x8*)((s) + bBase + 8192 + n * 1024 + cOff0);\
        b1[n][1] = *(const bf16x8*)((s) + bBase + 8192 + n * 1024 + cOff1);\
    } } while (0)

#define READ_A1(s) do {                                                    \
    _Pragma("unroll") for (int m = 0; m < 4; ++m) {                        \
        a1[m][0] = *(const bf16x8*)((s) + 8192 + aBase + m * 1024 + cOff0);\
        a1[m][1] = *(const bf16x8*)((s) + 8192 + aBase + m * 1024 + cOff1);\
    } } while (0)

    // MFMA clusters (operands read in an EARLIER phase; zero-wait)
#define MFMA_Q0() do { _Pragma("unroll") for (int kk = 0; kk < 2; ++kk)    \
    _Pragma("unroll") for (int m = 0; m < 4; ++m)                          \
    _Pragma("unroll") for (int n = 0; n < 2; ++n)                          \
        acc[m][n] = MFMA(a0[m][kk], b0[n][kk], acc[m][n]); } while (0)
#define MFMA_Q1() do { _Pragma("unroll") for (int kk = 0; kk < 2; ++kk)    \
    _Pragma("unroll") for (int m = 0; m < 4; ++m)                          \
    _Pragma("unroll") for (int n = 0; n < 2; ++n)                          \
        acc[m][2 + n] = MFMA(a0[m][kk], b1[n][kk], acc[m][2 + n]); } while (0)
#define MFMA_Q2() do { _Pragma("unroll") for (int kk = 0; kk < 2; ++kk)    \
    _Pragma("unroll") for (int m = 0; m < 4; ++m)                          \
    _Pragma("unroll") for (int n = 0; n < 2; ++n)                          \
        acc[4 + m][n] = MFMA(a1[m][kk], b0[n][kk], acc[4 + m][n]); } while (0)
#define MFMA_Q3() do { _Pragma("unroll") for (int kk = 0; kk < 2; ++kk)    \
    _Pragma("unroll") for (int m = 0; m < 4; ++m)                          \
    _Pragma("unroll") for (int n = 0; n < 2; ++n)                          \
        acc[4 + m][2 + n] = MFMA(a1[m][kk], b1[n][kk], acc[4 + m][2 + n]); } while (0)

    // per-wave drain of own ds_reads before the phase barrier (WAR publish)
#define LGKM0_SB()                                                         \
    asm volatile("s_waitcnt lgkmcnt(0)" ::: "memory");                     \
    __builtin_amdgcn_sched_barrier(0)

#define END_BARRIER()                                                      \
    __builtin_amdgcn_s_barrier();                                          \
    FENCE()

    // prologue: tile0 all 4 regions (8 loads) | tile1 minus Am1 (6 loads).
    STAGE_A(0, 0, 0); STAGE_A(0, 0, 1); STAGE_B(0, 0, 0); STAGE_B(0, 0, 1);
    FENCE();
    STAGE_A(1, 1, 0); STAGE_B(1, 1, 0); STAGE_B(1, 1, 1);
    FENCE();
    asm volatile("s_waitcnt vmcnt(6)" ::: "memory");   // tile0 landed
    __builtin_amdgcn_sched_barrier(0);
    END_BARRIER();

    const bf16_t* s0 = (const bf16_t*)sm;           // buf0 (even tiles)
    const bf16_t* s1 = (const bf16_t*)sm + 32768;   // buf1 (odd tiles)

    // ---- peeled P1(0): reads a0,b0 of tile0; stage Am1(b1,tile1) ----
    READ_A0B0(s0);
    STAGE_A(1, 1, 1);
    FENCE();
    LGKM0_SB();
    END_BARRIER();

    for (int i = 0; i < NITER; ++i) {
        const int tk0 = 2 * i;
        const int tk1 = 2 * i + 1;
        const bool full = (i < NITER - 1);

        // ===== P2: reads b1(s0); stage Am0(b0,tk0+2); MFMA q0(tk0) =====
        READ_B1(s0);
        if (full) STAGE_A(0, tk0 + 2, 0);
        FENCE();
        __builtin_amdgcn_sched_barrier(0);
        __builtin_amdgcn_s_setprio(1);
        MFMA_Q0();
        __builtin_amdgcn_s_setprio(0);
        LGKM0_SB();
        END_BARRIER();

        // ===== P3: reads a1(s0); stage Bn0(b0,tk0+2); MFMA q1(tk0) =====
        READ_A1(s0);
        if (full) STAGE_B(0, tk0 + 2, 0);
        FENCE();
        __builtin_amdgcn_sched_barrier(0);
        __builtin_amdgcn_s_setprio(1);
        MFMA_Q1();
        __builtin_amdgcn_s_setprio(0);
        LGKM0_SB();
        END_BARRIER();

        // ===== P4: stage Bn1(b0,tk0+2); MFMA q2(tk0); vmcnt(6) =====
        if (full) STAGE_B(0, tk0 + 2, 1);
        FENCE();
        __builtin_amdgcn_sched_barrier(0);
        __builtin_amdgcn_s_setprio(1);
        MFMA_Q2();
        __builtin_amdgcn_s_setprio(0);
        if (full) asm volatile("s_waitcnt vmcnt(6)" ::: "memory");
        else      asm volatile("s_waitcnt vmcnt(0)" ::: "memory");
        __builtin_amdgcn_sched_barrier(0);
        END_BARRIER();

        // ===== P5: reads a0,b0(s1); stage Am1(b0,tk0+2); MFMA q3(tk0) ===
        READ_A0B0(s1);
        if (full) STAGE_A(0, tk0 + 2, 1);
        FENCE();
        __builtin_amdgcn_sched_barrier(0);
        __builtin_amdgcn_s_setprio(1);
        MFMA_Q3();
        __builtin_amdgcn_s_setprio(0);
        LGKM0_SB();
        END_BARRIER();

        // ===== P6: reads b1(s1); stage Am0(b1,tk1+2); MFMA q0(tk1) =====
        READ_B1(s1);
        if (full) STAGE_A(1, tk1 + 2, 0);
        FENCE();
        __builtin_amdgcn_sched_barrier(0);
        __builtin_amdgcn_s_setprio(1);
        MFMA_Q0();
        __builtin_amdgcn_s_setprio(0);
        LGKM0_SB();
        END_BARRIER();

        // ===== P7: reads a1(s1); stage Bn0(b1,tk1+2); MFMA q1(tk1) =====
        READ_A1(s1);
        if (full) STAGE_B(1, tk1 + 2, 0);
        FENCE();
        __builtin_amdgcn_sched_barrier(0);
        __builtin_amdgcn_s_setprio(1);
        MFMA_Q1();
        __builtin_amdgcn_s_setprio(0);
        LGKM0_SB();
        END_BARRIER();

        // ===== P8: stage Bn1(b1,tk1+2); MFMA q2(tk1); vmcnt(6) =====
        if (full) STAGE_B(1, tk1 + 2, 1);
        FENCE();
        __builtin_amdgcn_sched_barrier(0);
        __builtin_amdgcn_s_setprio(1);
        MFMA_Q2();
        __builtin_amdgcn_s_setprio(0);
        if (full) asm volatile("s_waitcnt vmcnt(6)" ::: "memory");
        else      asm volatile("s_waitcnt vmcnt(0)" ::: "memory");
        __builtin_amdgcn_sched_barrier(0);
        END_BARRIER();

        // ===== P1+: reads a0,b0(s0,tk0+2); stage Am1(b1,tk1+2); q3(tk1) ==
        if (full) {
            READ_A0B0(s0);
            STAGE_A(1, tk1 + 2, 1);
        }
        FENCE();
        __builtin_amdgcn_sched_barrier(0);
        __builtin_amdgcn_s_setprio(1);
        MFMA_Q3();
        __builtin_amdgcn_s_setprio(0);
        LGKM0_SB();
        END_BARRIER();
    }

#undef STAGE_A
#undef STAGE_B

    // epilogue: C/D layout col = lane&15, row = (lane>>4)*4 + j
    const long cb = blockN + wc * 64;
    float bv[4];
    long  cn[4];
#pragma unroll
    for (int n = 0; n < 4; ++n) {
        cn[n] = cb + n * 16 + l15;
        bv[n] = bias[cn[n]];
    }
#pragma unroll
    for (int m = 0; m < 8; ++m) {
        const long r0 = blockM + wr * 128 + m * 16 + lk * 4;
#pragma unroll
        for (int n = 0; n < 4; ++n)
#pragma unroll
            for (int j = 0; j < 4; ++j)
                C[(r0 + j) * (long)N_DIM + cn[n]] = acc[m][n][j] + bv[n];
    }
}

// ---------------- fp32 fallback (only if ws too small) ---------------------
__global__ void __launch_bounds__(256) gemm_f32_fallback(
    const float* __restrict__ A, const float* __restrict__ W,
    const float* __restrict__ bias, float* __restrict__ C)
{
    __shared__ float sA[64][17];
    __shared__ float sB[64][17];
    const int bm = blockIdx.y, bn = blockIdx.x;
    const int t = threadIdx.x;
    const int tx = t & 15, ty = t >> 4;
    const long row0 = (long)bm * 64, col0 = (long)bn * 64;
    float acc[4][4] = {};
    for (int kt = 0; kt < K_DIM; kt += 16) {
        const int r = t >> 2, c = (t & 3) * 4;
        float4 a4 = *(const float4*)&A[(row0 + r) * K_DIM + kt + c];
        float4 b4 = *(const float4*)&W[(col0 + r) * K_DIM + kt + c];
        sA[r][c] = a4.x; sA[r][c + 1] = a4.y; sA[r][c + 2] = a4.z; sA[r][c + 3] = a4.w;
        sB[r][c] = b4.x; sB[r][c + 1] = b4.y; sB[r][c + 2] = b4.z; sB[r][c + 3] = b4.w;
        __syncthreads();
#pragma unroll
        for (int kk = 0; kk < 16; ++kk) {
            float av[4], bv[4];
#pragma unroll
            for (int i = 0; i < 4; ++i) av[i] = sA[ty * 4 + i][kk];
#pragma unroll
            for (int j = 0; j < 4; ++j) bv[j] = sB[tx * 4 + j][kk];
#pragma unroll
            for (int i = 0; i < 4; ++i)
#pragma unroll
                for (int j = 0; j < 4; ++j) acc[i][j] += av[i] * bv[j];
        }
        __syncthreads();
    }
#pragma unroll
    for (int i = 0; i < 4; ++i)
#pragma unroll
        for (int j = 0; j < 4; ++j)
            C[(row0 + ty * 4 + i) * N_DIM + col0 + tx * 4 + j] =
                acc[i][j] + bias[col0 + tx * 4 + j];
}

extern "C" void kernel_launch(void* const* d_in, const int* in_sizes, int n_in,
                              void* d_out, int out_size, void* d_ws, size_t ws_size,
                              hipStream_t stream)
{
    const float* x = (const float*)d_in[0];   // [8192, 4096]
    const float* W = (const float*)d_in[1];   // [4096, 4096]
    const float* b = (const float*)d_in[2];   // [4096]
    float* out = (float*)d_out;               // [8192, 4096] fp32

    const long xe = (long)M_DIM * K_DIM;
    const long we = (long)N_DIM * K_DIM;
    const size_t need = (size_t)(xe + we) * sizeof(bf16_t);  // ~96 MiB

    if (ws_size >= need) {
        bf16_t* xb = (bf16_t*)d_ws;
        bf16_t* wb = xb + xe;
        cvt_f32_bf16<<<2048, 256, 0, stream>>>(x, xb, xe / 8);
        cvt_f32_bf16<<<1024, 256, 0, stream>>>(W, wb, we / 8);
        gemm_256_8ph<<<(M_DIM / 256) * (N_DIM / 256), 512, 0, stream>>>(xb, wb, b, out);
    } else {
        dim3 grid(N_DIM / 64, M_DIM / 64);
        gemm_f32_fallback<<<grid, 256, 0, stream>>>(x, W, b, out);
    }
}